// Round 29
// baseline (210.000 us; speedup 1.0000x reference)
//
#include <hip/hip_runtime.h>
#include <hip/hip_bf16.h>

typedef __bf16 bf16_t;
typedef __bf16 bf16x8 __attribute__((ext_vector_type(8)));
typedef float f32x4 __attribute__((ext_vector_type(4)));

#define MFMA16(a, b, c) __builtin_amdgcn_mfma_f32_16x16x32_bf16((a), (b), (c), 0, 0, 0)

static constexpr int S_LEN = 2048;
static constexpr int DM = 1024;
static constexpr int NH = 16;
static constexpr int DH = 64;

typedef const __attribute__((address_space(1))) unsigned int gu32;
typedef __attribute__((address_space(3))) unsigned int lu32;
__device__ __forceinline__ void gl_lds16(const void* src, void* dst) {
    __builtin_amdgcn_global_load_lds((gu32*)src, (lu32*)dst, 16, 0, 0);
}

// ================= pre-pass: weight transpose + bf16 convert (only) ==============
struct PreArgs { const float* w[4]; bf16_t* o[4]; };

__global__ __launch_bounds__(256) void pre_kernel(PreArgs p) {
    int bid = blockIdx.x;
    int tid = threadIdx.x;
    int wi = bid >> 8;
    int tb = bid & 255;
    int k0 = (tb >> 4) * 64;
    int n0 = (tb & 15) * 64;
    const float* w = p.w[wi];
    bf16_t* o = p.o[wi];
    __shared__ bf16_t t[64 * 66];
#pragma unroll
    for (int i = 0; i < 4; ++i) {
        int f = tid + 256 * i;
        int row = f >> 4;
        int c4 = f & 15;
        f32x4 v = *reinterpret_cast<const f32x4*>(w + (size_t)(k0 + row) * DM + n0 + c4 * 4);
        int base = row * 66 + c4 * 4;
        t[base + 0] = (bf16_t)v[0];
        t[base + 1] = (bf16_t)v[1];
        t[base + 2] = (bf16_t)v[2];
        t[base + 3] = (bf16_t)v[3];
    }
    __syncthreads();
#pragma unroll
    for (int i = 0; i < 2; ++i) {
        int c = tid + 256 * i;
        int n = c >> 3;
        int ck = c & 7;
        union { bf16_t h[8]; uint4 u; } cv;
#pragma unroll
        for (int j = 0; j < 8; ++j) cv.h[j] = t[(ck * 8 + j) * 66 + n];
        *reinterpret_cast<uint4*>(o + (size_t)(n0 + n) * DM + k0 + ck * 8) = cv.u;
    }
}

// ====== fused QKV projection: 128x64 tiles, f32-A direct staging (cast fused) ====
struct QKVArgs {
    const float* A[3]; const bf16_t* BT[3]; const float* bias[3];
    bf16_t* out[3]; float alpha0;
};

__global__ __launch_bounds__(256) void gemm_qkv(QKVArgs a) {
    constexpr int K = 1024;
    int bid = blockIdx.x;
    int wi = bid >> 10;
    int sub = bid & 1023;
    int bm = (sub & 7) * 8 + ((sub >> 3) & 7);   // [0,64)  XCD-grouped
    int bn = sub >> 6;                           // [0,16)
    int tid = threadIdx.x;
    int w = tid >> 6, l = tid & 63;
    int g = l >> 4, lc = l & 15;

    const float* Af = a.A[wi];
    const bf16_t* BT = a.BT[wi];

    __shared__ float  a_buf[2][128 * 32];        // 16 KB x2 (f32 tile)
    __shared__ bf16_t b_buf[2][64 * 32];         // 4 KB x2  -> 40 KB total

    f32x4 zero = {0.f, 0.f, 0.f, 0.f};
    f32x4 acc[4][2];
#pragma unroll
    for (int m = 0; m < 4; ++m)
#pragma unroll
        for (int n = 0; n < 2; ++n) acc[m][n] = zero;

    int m0 = bm * 128, n0 = bn * 64;
    int wr = (w >> 1) * 64, wc = (w & 1) * 32;

    int sc8 = (l & 7) ^ (l >> 3);                // A: pre-swizzled src chunk [0,8)
    int scw = (l & 3) ^ ((l >> 3) & 3);          // B: pre-swizzled src chunk [0,4)
    int sw8 = lc & 7;                            // A read-side swizzle key
    int fsw = (lc >> 1) & 3;                     // B read-side swizzle key

    auto stage = [&](int buf, int kt) {          // 5 gl_lds per thread
        int k0 = kt * 32;
#pragma unroll
        for (int i = 0; i < 4; ++i) {
            int r8 = (w * 4 + i) * 8;            // 8 f32 rows per issue
            int row = r8 + (l >> 3);
            gl_lds16(Af + (size_t)(m0 + row) * K + k0 + sc8 * 4, &a_buf[buf][r8 * 32]);
        }
        int r16 = w * 16;
        int row = r16 + (l >> 2);
        gl_lds16(BT + (size_t)(n0 + row) * K + k0 + scw * 8, &b_buf[buf][r16 * 32]);
    };

    stage(0, 0);
    int cur = 0;
    for (int kt = 0; kt < K / 32; ++kt) {
        __syncthreads();
        if (kt + 1 < K / 32) stage(cur ^ 1, kt + 1);
        bf16x8 af[4], bfr[2];
#pragma unroll
        for (int m = 0; m < 4; ++m) {
            const float* base = &a_buf[cur][(wr + m * 16 + lc) * 32];
            f32x4 lo = *reinterpret_cast<const f32x4*>(base + (((2 * g) ^ sw8) << 2));
            f32x4 hi = *reinterpret_cast<const f32x4*>(base + (((2 * g + 1) ^ sw8) << 2));
            union { bf16_t h[8]; bf16x8 v; } cv;
#pragma unroll
            for (int j = 0; j < 4; ++j) { cv.h[j] = (bf16_t)lo[j]; cv.h[4 + j] = (bf16_t)hi[j]; }
            af[m] = cv.v;
        }
#pragma unroll
        for (int n = 0; n < 2; ++n)
            bfr[n] = *reinterpret_cast<bf16x8*>(
                &b_buf[cur][(wc + n * 16 + lc) * 32 + (g ^ fsw) * 8]);
#pragma unroll
        for (int m = 0; m < 4; ++m)
#pragma unroll
            for (int n = 0; n < 2; ++n)
                acc[m][n] = MFMA16(af[m], bfr[n], acc[m][n]);
        cur ^= 1;
    }

    float alpha = (wi == 0) ? a.alpha0 : 1.0f;
    const float* bias = a.bias[wi];
    bf16_t* Cp = a.out[wi];
    if (wi == 2) {
        // V: transposed [B][H][dh][S], packed 8B stores
#pragma unroll
        for (int n = 0; n < 2; ++n) {
            int ng = n0 + wc + n * 16 + lc;
            float bv = bias[ng];
            int h = ng >> 6, d = ng & 63;
#pragma unroll
            for (int m = 0; m < 4; ++m) {
                int s0g = m0 + wr + m * 16 + g * 4;
                int b = s0g >> 11, s0 = s0g & 2047;
                union { bf16_t hh[4]; uint2 u; } pk;
#pragma unroll
                for (int r = 0; r < 4; ++r)
                    pk.hh[r] = (bf16_t)(acc[m][n][r] + bv);
                *reinterpret_cast<uint2*>(
                    &Cp[(((size_t)(b * NH + h)) * DH + d) * S_LEN + s0]) = pk.u;
            }
        }
    } else {
        // Q/K: [B][H][S][dh]
#pragma unroll
        for (int n = 0; n < 2; ++n) {
            int ng = n0 + wc + n * 16 + lc;
            float bv = bias[ng];
            int h = ng >> 6, d = ng & 63;
#pragma unroll
            for (int m = 0; m < 4; ++m) {
#pragma unroll
                for (int r = 0; r < 4; ++r) {
                    int mg = m0 + wr + m * 16 + g * 4 + r;
                    int b = mg >> 11, s = mg & 2047;
                    Cp[(((size_t)(b * NH + h)) * S_LEN + s) * DH + d] =
                        (bf16_t)((acc[m][n][r] + bv) * alpha);
                }
            }
        }
    }
}

// ======== final projection: C[M][1024] f32, 128x64 tiles + T2 chunk-swizzle ======
__global__ __launch_bounds__(256) void gemm_o(const bf16_t* __restrict__ Ab,
                                              const bf16_t* __restrict__ BT,
                                              const float* __restrict__ bias,
                                              float* __restrict__ Cp) {
    constexpr int K = 1024, N = 1024;
    int bid = blockIdx.x;
    int bm = (bid & 7) * 8 + ((bid >> 3) & 7);
    int bn = bid >> 6;
    int tid = threadIdx.x;
    int w = tid >> 6, l = tid & 63;
    int g = l >> 4, lc = l & 15;

    __shared__ bf16_t a_buf[2][128 * 32];
    __shared__ bf16_t b_buf[2][64 * 32];

    f32x4 zero = {0.f, 0.f, 0.f, 0.f};
    f32x4 acc[4][2];
#pragma unroll
    for (int m = 0; m < 4; ++m)
#pragma unroll
        for (int n = 0; n < 2; ++n) acc[m][n] = zero;

    int m0 = bm * 128, n0 = bn * 64;
    int wr = (w >> 1) * 64, wc = (w & 1) * 32;

    int scw = (l & 3) ^ ((l >> 3) & 3);
    int fsw = (lc >> 1) & 3;

    auto stage = [&](int buf, int kt) {
        int k0 = kt * 32;
#pragma unroll
        for (int i = 0; i < 2; ++i) {
            int r16 = (w * 2 + i) * 16;
            int row = r16 + (l >> 2);
            gl_lds16(Ab + (size_t)(m0 + row) * K + k0 + scw * 8, &a_buf[buf][r16 * 32]);
        }
        int r16 = w * 16;
        int row = r16 + (l >> 2);
        gl_lds16(BT + (size_t)(n0 + row) * K + k0 + scw * 8, &b_buf[buf][r16 * 32]);
    };

    stage(0, 0);
    int cur = 0;
    for (int kt = 0; kt < K / 32; ++kt) {
        __syncthreads();
        if (kt + 1 < K / 32) stage(cur ^ 1, kt + 1);
        bf16x8 af[4], bfr[2];
#pragma unroll
        for (int m = 0; m < 4; ++m)
            af[m] = *reinterpret_cast<bf16x8*>(
                &a_buf[cur][(wr + m * 16 + lc) * 32 + (g ^ fsw) * 8]);
#pragma unroll
        for (int n = 0; n < 2; ++n)
            bfr[n] = *reinterpret_cast<bf16x8*>(
                &b_buf[cur][(wc + n * 16 + lc) * 32 + (g ^ fsw) * 8]);
#pragma unroll
        for (int m = 0; m < 4; ++m)
#pragma unroll
            for (int n = 0; n < 2; ++n)
                acc[m][n] = MFMA16(af[m], bfr[n], acc[m][n]);
        cur ^= 1;
    }

#pragma unroll
    for (int n = 0; n < 2; ++n) {
        int ng = n0 + wc + n * 16 + lc;
        float bv = bias[ng];
#pragma unroll
        for (int m = 0; m < 4; ++m) {
#pragma unroll
            for (int r = 0; r < 4; ++r) {
                int mg = m0 + wr + m * 16 + g * 4 + r;
                Cp[(size_t)mg * N + ng] = acc[m][n][r] + bv;
            }
        }
    }
}

// ======= causal flash attention (2048 blocks, descending, hoisted pointers) ======
__global__ __launch_bounds__(256) void attn_kernel(const bf16_t* __restrict__ Qh,
                                                   const bf16_t* __restrict__ Kh,
                                                   const bf16_t* __restrict__ Vt,
                                                   bf16_t* __restrict__ AO) {
    int bid = blockIdx.x;
    int qt = 31 - (bid >> 6);
    int bh = bid & 63;
    int h = bh & 15;
    int b = bh >> 4;
    int tid = threadIdx.x;
    int w = tid >> 6, l = tid & 63;
    int g = l >> 4, lc = l & 15;
    int q0 = qt * 64 + w * 16;
    int q = q0 + lc;

    __shared__ bf16_t k_lds[2][64 * 64];
    __shared__ bf16_t v_lds[2][64 * 64];
    __shared__ bf16_t p_lds[4][16 * 64];

    size_t head_off = ((size_t)(b * NH + h)) * S_LEN * DH;

    bf16x8 qf[2];
    {
        const bf16_t* qp = Qh + head_off + (size_t)(q0 + lc) * DH + g * 8;
        qf[0] = *reinterpret_cast<const bf16x8*>(qp);
        qf[1] = *reinterpret_cast<const bf16x8*>(qp + 32);
    }

    const bf16_t* kg0; const bf16_t* kg1; const bf16_t* vg0; const bf16_t* vg1;
    int r8a = w * 16, r8b = w * 16 + 8;
    {
        const bf16_t* Kp = Kh + head_off;
        const bf16_t* Vp = Vt + head_off;
        int rowa = r8a + (l >> 3), rowb = r8b + (l >> 3);
        int sca = (l & 7) ^ (rowa & 7), scb = (l & 7) ^ (rowb & 7);
        kg0 = Kp + (size_t)rowa * DH + sca * 8;
        kg1 = Kp + (size_t)rowb * DH + scb * 8;
        vg0 = Vp + (size_t)rowa * S_LEN + sca * 8;
        vg1 = Vp + (size_t)rowb * S_LEN + scb * 8;
    }

    f32x4 zero = {0.f, 0.f, 0.f, 0.f};
    f32x4 o_acc[4];
#pragma unroll
    for (int nt = 0; nt < 4; ++nt) o_acc[nt] = zero;
    float l_part = 0.f;

    int sw = lc & 7;

    auto stageKV = [&](int buf) {
        gl_lds16(kg0, &k_lds[buf][r8a * 64]);
        gl_lds16(vg0, &v_lds[buf][r8a * 64]);
        gl_lds16(kg1, &k_lds[buf][r8b * 64]);
        gl_lds16(vg1, &v_lds[buf][r8b * 64]);
    };

    stageKV(0);
    int cur = 0;
    for (int t = 0; t <= qt; ++t) {
        int kv0 = t * 64;
        __syncthreads();
        if (t < qt) {
            kg0 += 64 * DH; kg1 += 64 * DH; vg0 += 64; vg1 += 64;
            stageKV(cur ^ 1);
        }

        f32x4 sc[4];
#pragma unroll
        for (int nt = 0; nt < 4; ++nt) {
            int row = nt * 16 + lc;
            bf16x8 kf0 = *reinterpret_cast<bf16x8*>(&k_lds[cur][row * 64 + ((g) ^ sw) * 8]);
            bf16x8 kf1 = *reinterpret_cast<bf16x8*>(&k_lds[cur][row * 64 + ((4 + g) ^ sw) * 8]);
            f32x4 s = zero;
            s = MFMA16(kf0, qf[0], s);
            s = MFMA16(kf1, qf[1], s);
            sc[nt] = s;
        }
        if (t == qt) {
#pragma unroll
            for (int nt = 0; nt < 4; ++nt)
#pragma unroll
                for (int r = 0; r < 4; ++r) {
                    int kv = kv0 + nt * 16 + g * 4 + r;
                    if (kv > q) sc[nt][r] = -1e30f;
                }
        }
#pragma unroll
        for (int nt = 0; nt < 4; ++nt)
#pragma unroll
            for (int r = 0; r < 4; ++r) sc[nt][r] = exp2f(sc[nt][r]);
#pragma unroll
        for (int nt = 0; nt < 4; ++nt)
            l_part += sc[nt][0] + sc[nt][1] + sc[nt][2] + sc[nt][3];
#pragma unroll
        for (int nt = 0; nt < 4; ++nt) {
            union { bf16_t hh[4]; uint2 u; } pk;
#pragma unroll
            for (int r = 0; r < 4; ++r) pk.hh[r] = (bf16_t)sc[nt][r];
            int cu = nt * 2 + (g >> 1);
            *reinterpret_cast<uint2*>(
                &p_lds[w][lc * 64 + ((cu ^ sw) * 8) + (g & 1) * 4]) = pk.u;
        }
        bf16x8 pf0 = *reinterpret_cast<bf16x8*>(&p_lds[w][lc * 64 + ((g) ^ sw) * 8]);
        bf16x8 pf1 = *reinterpret_cast<bf16x8*>(&p_lds[w][lc * 64 + ((4 + g) ^ sw) * 8]);
#pragma unroll
        for (int nt = 0; nt < 4; ++nt) {
            int row = nt * 16 + lc;
            bf16x8 vf0 = *reinterpret_cast<bf16x8*>(&v_lds[cur][row * 64 + ((g) ^ sw) * 8]);
            bf16x8 vf1 = *reinterpret_cast<bf16x8*>(&v_lds[cur][row * 64 + ((4 + g) ^ sw) * 8]);
            o_acc[nt] = MFMA16(pf0, vf0, o_acc[nt]);
            o_acc[nt] = MFMA16(pf1, vf1, o_acc[nt]);
        }
        cur ^= 1;
    }

    float l_s = l_part;
    l_s += __shfl_xor(l_s, 16, 64);
    l_s += __shfl_xor(l_s, 32, 64);

#pragma unroll
    for (int r = 0; r < 4; ++r) {
        float lr = __shfl(l_s, g * 4 + r, 64);
        float inv = 1.0f / lr;
        int qq = q0 + g * 4 + r;
        size_t base = ((size_t)b * S_LEN + qq) * DM + h * DH;
#pragma unroll
        for (int nt = 0; nt < 4; ++nt)
            AO[base + nt * 16 + lc] = (bf16_t)(o_acc[nt][r] * inv);
    }
}

// ================= launch =================
extern "C" void kernel_launch(void* const* d_in, const int* in_sizes, int n_in,
                              void* d_out, int out_size, void* d_ws, size_t ws_size,
                              hipStream_t stream) {
    (void)in_sizes; (void)n_in; (void)out_size; (void)ws_size;
    const float* query = (const float*)d_in[0];
    const float* key   = (const float*)d_in[1];
    const float* value = (const float*)d_in[2];
    const float* wq = (const float*)d_in[3];
    const float* bq = (const float*)d_in[4];
    const float* wk = (const float*)d_in[5];
    const float* bk = (const float*)d_in[6];
    const float* wv = (const float*)d_in[7];
    const float* bv = (const float*)d_in[8];
    const float* wo = (const float*)d_in[9];
    const float* bo = (const float*)d_in[10];
    float* out = (float*)d_out;

    char* ws = (char*)d_ws;
    const size_t Mi = (size_t)1 << 20;
    bf16_t* wqT = (bf16_t*)(ws + 0 * Mi);
    bf16_t* wkT = (bf16_t*)(ws + 2 * Mi);
    bf16_t* wvT = (bf16_t*)(ws + 4 * Mi);
    bf16_t* woT = (bf16_t*)(ws + 6 * Mi);
    bf16_t* Qh  = (bf16_t*)(ws + 8 * Mi);   // [B][H][S][64]
    bf16_t* Kh  = (bf16_t*)(ws + 24 * Mi);  // [B][H][S][64]
    bf16_t* Vt  = (bf16_t*)(ws + 40 * Mi);  // [B][H][64][S]
    bf16_t* AO  = (bf16_t*)(ws + 56 * Mi);  // [B][S][1024]

    const float QALPHA = 0.04508422f;        // log2(e)/32

    PreArgs p;
    p.w[0] = wq; p.w[1] = wk; p.w[2] = wv; p.w[3] = wo;
    p.o[0] = wqT; p.o[1] = wkT; p.o[2] = wvT; p.o[3] = woT;
    pre_kernel<<<dim3(1024), dim3(256), 0, stream>>>(p);

    QKVArgs qa;
    qa.A[0] = query; qa.A[1] = key; qa.A[2] = value;
    qa.BT[0] = wqT; qa.BT[1] = wkT; qa.BT[2] = wvT;
    qa.bias[0] = bq; qa.bias[1] = bk; qa.bias[2] = bv;
    qa.out[0] = Qh; qa.out[1] = Kh; qa.out[2] = Vt;
    qa.alpha0 = QALPHA;
    gemm_qkv<<<dim3(3 * 1024), dim3(256), 0, stream>>>(qa);

    attn_kernel<<<dim3(2048), dim3(256), 0, stream>>>(Qh, Kh, Vt, AO);

    gemm_o<<<dim3(1024), dim3(256), 0, stream>>>(AO, woT, bo, out);
}

// Round 30
// 209.355 us; speedup vs baseline: 1.0031x; 1.0031x over previous
//
#include <hip/hip_runtime.h>
#include <hip/hip_bf16.h>

typedef __bf16 bf16_t;
typedef __bf16 bf16x8 __attribute__((ext_vector_type(8)));
typedef float f32x4 __attribute__((ext_vector_type(4)));

#define MFMA16(a, b, c) __builtin_amdgcn_mfma_f32_16x16x32_bf16((a), (b), (c), 0, 0, 0)

static constexpr int S_LEN = 2048;
static constexpr int DM = 1024;
static constexpr int NH = 16;
static constexpr int DH = 64;

typedef const __attribute__((address_space(1))) unsigned int gu32;
typedef __attribute__((address_space(3))) unsigned int lu32;
__device__ __forceinline__ void gl_lds16(const void* src, void* dst) {
    __builtin_amdgcn_global_load_lds((gu32*)src, (lu32*)dst, 16, 0, 0);
}

// ================= pre-pass: weight transpose + bf16 convert (only) ==============
struct PreArgs { const float* w[4]; bf16_t* o[4]; };

__global__ __launch_bounds__(256) void pre_kernel(PreArgs p) {
    int bid = blockIdx.x;
    int tid = threadIdx.x;
    int wi = bid >> 8;
    int tb = bid & 255;
    int k0 = (tb >> 4) * 64;
    int n0 = (tb & 15) * 64;
    const float* w = p.w[wi];
    bf16_t* o = p.o[wi];
    __shared__ bf16_t t[64 * 66];
#pragma unroll
    for (int i = 0; i < 4; ++i) {
        int f = tid + 256 * i;
        int row = f >> 4;
        int c4 = f & 15;
        f32x4 v = *reinterpret_cast<const f32x4*>(w + (size_t)(k0 + row) * DM + n0 + c4 * 4);
        int base = row * 66 + c4 * 4;
        t[base + 0] = (bf16_t)v[0];
        t[base + 1] = (bf16_t)v[1];
        t[base + 2] = (bf16_t)v[2];
        t[base + 3] = (bf16_t)v[3];
    }
    __syncthreads();
#pragma unroll
    for (int i = 0; i < 2; ++i) {
        int c = tid + 256 * i;
        int n = c >> 3;
        int ck = c & 7;
        union { bf16_t h[8]; uint4 u; } cv;
#pragma unroll
        for (int j = 0; j < 8; ++j) cv.h[j] = t[(ck * 8 + j) * 66 + n];
        *reinterpret_cast<uint4*>(o + (size_t)(n0 + n) * DM + k0 + ck * 8) = cv.u;
    }
}

// ====== fused QKV projection: 128x64 tiles, f32-A direct staging (cast fused) ====
struct QKVArgs {
    const float* A[3]; const bf16_t* BT[3]; const float* bias[3];
    bf16_t* out[3]; float alpha0;
};

__global__ __launch_bounds__(256) void gemm_qkv(QKVArgs a) {
    constexpr int K = 1024;
    int bid = blockIdx.x;
    int wi = bid >> 10;
    int sub = bid & 1023;
    int bm = (sub & 7) * 8 + ((sub >> 3) & 7);   // [0,64)  XCD-grouped
    int bn = sub >> 6;                           // [0,16)
    int tid = threadIdx.x;
    int w = tid >> 6, l = tid & 63;
    int g = l >> 4, lc = l & 15;

    const float* Af = a.A[wi];
    const bf16_t* BT = a.BT[wi];

    __shared__ float  a_buf[2][128 * 32];        // 16 KB x2 (f32 tile)
    __shared__ bf16_t b_buf[2][64 * 32];         // 4 KB x2  -> 40 KB total

    f32x4 zero = {0.f, 0.f, 0.f, 0.f};
    f32x4 acc[4][2];
#pragma unroll
    for (int m = 0; m < 4; ++m)
#pragma unroll
        for (int n = 0; n < 2; ++n) acc[m][n] = zero;

    int m0 = bm * 128, n0 = bn * 64;
    int wr = (w >> 1) * 64, wc = (w & 1) * 32;

    int sc8 = (l & 7) ^ (l >> 3);                // A: pre-swizzled src chunk [0,8)
    int scw = (l & 3) ^ ((l >> 3) & 3);          // B: pre-swizzled src chunk [0,4)
    int sw8 = lc & 7;                            // A read-side swizzle key
    int fsw = (lc >> 1) & 3;                     // B read-side swizzle key

    auto stage = [&](int buf, int kt) {          // 5 gl_lds per thread
        int k0 = kt * 32;
#pragma unroll
        for (int i = 0; i < 4; ++i) {
            int r8 = (w * 4 + i) * 8;            // 8 f32 rows per issue
            int row = r8 + (l >> 3);
            gl_lds16(Af + (size_t)(m0 + row) * K + k0 + sc8 * 4, &a_buf[buf][r8 * 32]);
        }
        int r16 = w * 16;
        int row = r16 + (l >> 2);
        gl_lds16(BT + (size_t)(n0 + row) * K + k0 + scw * 8, &b_buf[buf][r16 * 32]);
    };

    stage(0, 0);
    int cur = 0;
    for (int kt = 0; kt < K / 32; ++kt) {
        __syncthreads();
        if (kt + 1 < K / 32) stage(cur ^ 1, kt + 1);
        bf16x8 af[4], bfr[2];
#pragma unroll
        for (int m = 0; m < 4; ++m) {
            const float* base = &a_buf[cur][(wr + m * 16 + lc) * 32];
            f32x4 lo = *reinterpret_cast<const f32x4*>(base + (((2 * g) ^ sw8) << 2));
            f32x4 hi = *reinterpret_cast<const f32x4*>(base + (((2 * g + 1) ^ sw8) << 2));
            union { bf16_t h[8]; bf16x8 v; } cv;
#pragma unroll
            for (int j = 0; j < 4; ++j) { cv.h[j] = (bf16_t)lo[j]; cv.h[4 + j] = (bf16_t)hi[j]; }
            af[m] = cv.v;
        }
#pragma unroll
        for (int n = 0; n < 2; ++n)
            bfr[n] = *reinterpret_cast<bf16x8*>(
                &b_buf[cur][(wc + n * 16 + lc) * 32 + (g ^ fsw) * 8]);
#pragma unroll
        for (int m = 0; m < 4; ++m)
#pragma unroll
            for (int n = 0; n < 2; ++n)
                acc[m][n] = MFMA16(af[m], bfr[n], acc[m][n]);
        cur ^= 1;
    }

    float alpha = (wi == 0) ? a.alpha0 : 1.0f;
    const float* bias = a.bias[wi];
    bf16_t* Cp = a.out[wi];
    if (wi == 2) {
        // V: transposed [B][H][dh][S], packed 8B stores
#pragma unroll
        for (int n = 0; n < 2; ++n) {
            int ng = n0 + wc + n * 16 + lc;
            float bv = bias[ng];
            int h = ng >> 6, d = ng & 63;
#pragma unroll
            for (int m = 0; m < 4; ++m) {
                int s0g = m0 + wr + m * 16 + g * 4;
                int b = s0g >> 11, s0 = s0g & 2047;
                union { bf16_t hh[4]; uint2 u; } pk;
#pragma unroll
                for (int r = 0; r < 4; ++r)
                    pk.hh[r] = (bf16_t)(acc[m][n][r] + bv);
                *reinterpret_cast<uint2*>(
                    &Cp[(((size_t)(b * NH + h)) * DH + d) * S_LEN + s0]) = pk.u;
            }
        }
    } else {
        // Q/K: [B][H][S][dh]
#pragma unroll
        for (int n = 0; n < 2; ++n) {
            int ng = n0 + wc + n * 16 + lc;
            float bv = bias[ng];
            int h = ng >> 6, d = ng & 63;
#pragma unroll
            for (int m = 0; m < 4; ++m) {
#pragma unroll
                for (int r = 0; r < 4; ++r) {
                    int mg = m0 + wr + m * 16 + g * 4 + r;
                    int b = mg >> 11, s = mg & 2047;
                    Cp[(((size_t)(b * NH + h)) * S_LEN + s) * DH + d] =
                        (bf16_t)((acc[m][n][r] + bv) * alpha);
                }
            }
        }
    }
}

// ======== final projection: C[M][1024] f32, 128x64 tiles + T2 chunk-swizzle ======
__global__ __launch_bounds__(256) void gemm_o(const bf16_t* __restrict__ Ab,
                                              const bf16_t* __restrict__ BT,
                                              const float* __restrict__ bias,
                                              float* __restrict__ Cp) {
    constexpr int K = 1024, N = 1024;
    int bid = blockIdx.x;
    int bm = (bid & 7) * 8 + ((bid >> 3) & 7);
    int bn = bid >> 6;
    int tid = threadIdx.x;
    int w = tid >> 6, l = tid & 63;
    int g = l >> 4, lc = l & 15;

    __shared__ bf16_t a_buf[2][128 * 32];
    __shared__ bf16_t b_buf[2][64 * 32];

    f32x4 zero = {0.f, 0.f, 0.f, 0.f};
    f32x4 acc[4][2];
#pragma unroll
    for (int m = 0; m < 4; ++m)
#pragma unroll
        for (int n = 0; n < 2; ++n) acc[m][n] = zero;

    int m0 = bm * 128, n0 = bn * 64;
    int wr = (w >> 1) * 64, wc = (w & 1) * 32;

    int scw = (l & 3) ^ ((l >> 3) & 3);
    int fsw = (lc >> 1) & 3;

    auto stage = [&](int buf, int kt) {
        int k0 = kt * 32;
#pragma unroll
        for (int i = 0; i < 2; ++i) {
            int r16 = (w * 2 + i) * 16;
            int row = r16 + (l >> 2);
            gl_lds16(Ab + (size_t)(m0 + row) * K + k0 + scw * 8, &a_buf[buf][r16 * 32]);
        }
        int r16 = w * 16;
        int row = r16 + (l >> 2);
        gl_lds16(BT + (size_t)(n0 + row) * K + k0 + scw * 8, &b_buf[buf][r16 * 32]);
    };

    stage(0, 0);
    int cur = 0;
    for (int kt = 0; kt < K / 32; ++kt) {
        __syncthreads();
        if (kt + 1 < K / 32) stage(cur ^ 1, kt + 1);
        bf16x8 af[4], bfr[2];
#pragma unroll
        for (int m = 0; m < 4; ++m)
            af[m] = *reinterpret_cast<bf16x8*>(
                &a_buf[cur][(wr + m * 16 + lc) * 32 + (g ^ fsw) * 8]);
#pragma unroll
        for (int n = 0; n < 2; ++n)
            bfr[n] = *reinterpret_cast<bf16x8*>(
                &b_buf[cur][(wc + n * 16 + lc) * 32 + (g ^ fsw) * 8]);
#pragma unroll
        for (int m = 0; m < 4; ++m)
#pragma unroll
            for (int n = 0; n < 2; ++n)
                acc[m][n] = MFMA16(af[m], bfr[n], acc[m][n]);
        cur ^= 1;
    }

#pragma unroll
    for (int n = 0; n < 2; ++n) {
        int ng = n0 + wc + n * 16 + lc;
        float bv = bias[ng];
#pragma unroll
        for (int m = 0; m < 4; ++m) {
#pragma unroll
            for (int r = 0; r < 4; ++r) {
                int mg = m0 + wr + m * 16 + g * 4 + r;
                Cp[(size_t)mg * N + ng] = acc[m][n][r] + bv;
            }
        }
    }
}

// ======= causal flash attention (2048 blocks, descending, hoisted pointers) ======
__global__ __launch_bounds__(256) void attn_kernel(const bf16_t* __restrict__ Qh,
                                                   const bf16_t* __restrict__ Kh,
                                                   const bf16_t* __restrict__ Vt,
                                                   bf16_t* __restrict__ AO) {
    int bid = blockIdx.x;
    int qt = 31 - (bid >> 6);
    int bh = bid & 63;
    int h = bh & 15;
    int b = bh >> 4;
    int tid = threadIdx.x;
    int w = tid >> 6, l = tid & 63;
    int g = l >> 4, lc = l & 15;
    int q0 = qt * 64 + w * 16;
    int q = q0 + lc;

    __shared__ bf16_t k_lds[2][64 * 64];
    __shared__ bf16_t v_lds[2][64 * 64];
    __shared__ bf16_t p_lds[4][16 * 64];

    size_t head_off = ((size_t)(b * NH + h)) * S_LEN * DH;

    bf16x8 qf[2];
    {
        const bf16_t* qp = Qh + head_off + (size_t)(q0 + lc) * DH + g * 8;
        qf[0] = *reinterpret_cast<const bf16x8*>(qp);
        qf[1] = *reinterpret_cast<const bf16x8*>(qp + 32);
    }

    const bf16_t* kg0; const bf16_t* kg1; const bf16_t* vg0; const bf16_t* vg1;
    int r8a = w * 16, r8b = w * 16 + 8;
    {
        const bf16_t* Kp = Kh + head_off;
        const bf16_t* Vp = Vt + head_off;
        int rowa = r8a + (l >> 3), rowb = r8b + (l >> 3);
        int sca = (l & 7) ^ (rowa & 7), scb = (l & 7) ^ (rowb & 7);
        kg0 = Kp + (size_t)rowa * DH + sca * 8;
        kg1 = Kp + (size_t)rowb * DH + scb * 8;
        vg0 = Vp + (size_t)rowa * S_LEN + sca * 8;
        vg1 = Vp + (size_t)rowb * S_LEN + scb * 8;
    }

    f32x4 zero = {0.f, 0.f, 0.f, 0.f};
    f32x4 o_acc[4];
#pragma unroll
    for (int nt = 0; nt < 4; ++nt) o_acc[nt] = zero;
    float l_part = 0.f;

    int sw = lc & 7;

    auto stageKV = [&](int buf) {
        gl_lds16(kg0, &k_lds[buf][r8a * 64]);
        gl_lds16(vg0, &v_lds[buf][r8a * 64]);
        gl_lds16(kg1, &k_lds[buf][r8b * 64]);
        gl_lds16(vg1, &v_lds[buf][r8b * 64]);
    };

    stageKV(0);
    int cur = 0;
    for (int t = 0; t <= qt; ++t) {
        int kv0 = t * 64;
        __syncthreads();
        if (t < qt) {
            kg0 += 64 * DH; kg1 += 64 * DH; vg0 += 64; vg1 += 64;
            stageKV(cur ^ 1);
        }

        f32x4 sc[4];
#pragma unroll
        for (int nt = 0; nt < 4; ++nt) {
            int row = nt * 16 + lc;
            bf16x8 kf0 = *reinterpret_cast<bf16x8*>(&k_lds[cur][row * 64 + ((g) ^ sw) * 8]);
            bf16x8 kf1 = *reinterpret_cast<bf16x8*>(&k_lds[cur][row * 64 + ((4 + g) ^ sw) * 8]);
            f32x4 s = zero;
            s = MFMA16(kf0, qf[0], s);
            s = MFMA16(kf1, qf[1], s);
            sc[nt] = s;
        }
        if (t == qt) {
#pragma unroll
            for (int nt = 0; nt < 4; ++nt)
#pragma unroll
                for (int r = 0; r < 4; ++r) {
                    int kv = kv0 + nt * 16 + g * 4 + r;
                    if (kv > q) sc[nt][r] = -1e30f;
                }
        }
#pragma unroll
        for (int nt = 0; nt < 4; ++nt)
#pragma unroll
            for (int r = 0; r < 4; ++r) sc[nt][r] = exp2f(sc[nt][r]);
#pragma unroll
        for (int nt = 0; nt < 4; ++nt)
            l_part += sc[nt][0] + sc[nt][1] + sc[nt][2] + sc[nt][3];
#pragma unroll
        for (int nt = 0; nt < 4; ++nt) {
            union { bf16_t hh[4]; uint2 u; } pk;
#pragma unroll
            for (int r = 0; r < 4; ++r) pk.hh[r] = (bf16_t)sc[nt][r];
            int cu = nt * 2 + (g >> 1);
            *reinterpret_cast<uint2*>(
                &p_lds[w][lc * 64 + ((cu ^ sw) * 8) + (g & 1) * 4]) = pk.u;
        }
        bf16x8 pf0 = *reinterpret_cast<bf16x8*>(&p_lds[w][lc * 64 + ((g) ^ sw) * 8]);
        bf16x8 pf1 = *reinterpret_cast<bf16x8*>(&p_lds[w][lc * 64 + ((4 + g) ^ sw) * 8]);
#pragma unroll
        for (int nt = 0; nt < 4; ++nt) {
            int row = nt * 16 + lc;
            bf16x8 vf0 = *reinterpret_cast<bf16x8*>(&v_lds[cur][row * 64 + ((g) ^ sw) * 8]);
            bf16x8 vf1 = *reinterpret_cast<bf16x8*>(&v_lds[cur][row * 64 + ((4 + g) ^ sw) * 8]);
            o_acc[nt] = MFMA16(pf0, vf0, o_acc[nt]);
            o_acc[nt] = MFMA16(pf1, vf1, o_acc[nt]);
        }
        cur ^= 1;
    }

    float l_s = l_part;
    l_s += __shfl_xor(l_s, 16, 64);
    l_s += __shfl_xor(l_s, 32, 64);

#pragma unroll
    for (int r = 0; r < 4; ++r) {
        float lr = __shfl(l_s, g * 4 + r, 64);
        float inv = 1.0f / lr;
        int qq = q0 + g * 4 + r;
        size_t base = ((size_t)b * S_LEN + qq) * DM + h * DH;
#pragma unroll
        for (int nt = 0; nt < 4; ++nt)
            AO[base + nt * 16 + lc] = (bf16_t)(o_acc[nt][r] * inv);
    }
}

// ================= launch =================
extern "C" void kernel_launch(void* const* d_in, const int* in_sizes, int n_in,
                              void* d_out, int out_size, void* d_ws, size_t ws_size,
                              hipStream_t stream) {
    (void)in_sizes; (void)n_in; (void)out_size; (void)ws_size;
    const float* query = (const float*)d_in[0];
    const float* key   = (const float*)d_in[1];
    const float* value = (const float*)d_in[2];
    const float* wq = (const float*)d_in[3];
    const float* bq = (const float*)d_in[4];
    const float* wk = (const float*)d_in[5];
    const float* bk = (const float*)d_in[6];
    const float* wv = (const float*)d_in[7];
    const float* bv = (const float*)d_in[8];
    const float* wo = (const float*)d_in[9];
    const float* bo = (const float*)d_in[10];
    float* out = (float*)d_out;

    char* ws = (char*)d_ws;
    const size_t Mi = (size_t)1 << 20;
    bf16_t* wqT = (bf16_t*)(ws + 0 * Mi);
    bf16_t* wkT = (bf16_t*)(ws + 2 * Mi);
    bf16_t* wvT = (bf16_t*)(ws + 4 * Mi);
    bf16_t* woT = (bf16_t*)(ws + 6 * Mi);
    bf16_t* Qh  = (bf16_t*)(ws + 8 * Mi);   // [B][H][S][64]
    bf16_t* Kh  = (bf16_t*)(ws + 24 * Mi);  // [B][H][S][64]
    bf16_t* Vt  = (bf16_t*)(ws + 40 * Mi);  // [B][H][64][S]
    bf16_t* AO  = (bf16_t*)(ws + 56 * Mi);  // [B][S][1024]

    const float QALPHA = 0.04508422f;        // log2(e)/32

    PreArgs p;
    p.w[0] = wq; p.w[1] = wk; p.w[2] = wv; p.w[3] = wo;
    p.o[0] = wqT; p.o[1] = wkT; p.o[2] = wvT; p.o[3] = woT;
    pre_kernel<<<dim3(1024), dim3(256), 0, stream>>>(p);

    QKVArgs qa;
    qa.A[0] = query; qa.A[1] = key; qa.A[2] = value;
    qa.BT[0] = wqT; qa.BT[1] = wkT; qa.BT[2] = wvT;
    qa.bias[0] = bq; qa.bias[1] = bk; qa.bias[2] = bv;
    qa.out[0] = Qh; qa.out[1] = Kh; qa.out[2] = Vt;
    qa.alpha0 = QALPHA;
    gemm_qkv<<<dim3(3 * 1024), dim3(256), 0, stream>>>(qa);

    attn_kernel<<<dim3(2048), dim3(256), 0, stream>>>(Qh, Kh, Vt, AO);

    gemm_o<<<dim3(1024), dim3(256), 0, stream>>>(AO, woT, bo, out);
}

// Round 31
// 207.172 us; speedup vs baseline: 1.0137x; 1.0105x over previous
//
#include <hip/hip_runtime.h>
#include <hip/hip_bf16.h>

typedef __bf16 bf16_t;
typedef __bf16 bf16x8 __attribute__((ext_vector_type(8)));
typedef float f32x4 __attribute__((ext_vector_type(4)));

#define MFMA16(a, b, c) __builtin_amdgcn_mfma_f32_16x16x32_bf16((a), (b), (c), 0, 0, 0)

static constexpr int S_LEN = 2048;
static constexpr int DM = 1024;
static constexpr int NH = 16;
static constexpr int DH = 64;

typedef const __attribute__((address_space(1))) unsigned int gu32;
typedef __attribute__((address_space(3))) unsigned int lu32;
__device__ __forceinline__ void gl_lds16(const void* src, void* dst) {
    __builtin_amdgcn_global_load_lds((gu32*)src, (lu32*)dst, 16, 0, 0);
}

// ================= pre-pass: weight transpose + bf16 convert (only) ==============
struct PreArgs { const float* w[4]; bf16_t* o[4]; };

__global__ __launch_bounds__(256) void pre_kernel(PreArgs p) {
    int bid = blockIdx.x;
    int tid = threadIdx.x;
    int wi = bid >> 8;
    int tb = bid & 255;
    int k0 = (tb >> 4) * 64;
    int n0 = (tb & 15) * 64;
    const float* w = p.w[wi];
    bf16_t* o = p.o[wi];
    __shared__ bf16_t t[64 * 66];
#pragma unroll
    for (int i = 0; i < 4; ++i) {
        int f = tid + 256 * i;
        int row = f >> 4;
        int c4 = f & 15;
        f32x4 v = *reinterpret_cast<const f32x4*>(w + (size_t)(k0 + row) * DM + n0 + c4 * 4);
        int base = row * 66 + c4 * 4;
        t[base + 0] = (bf16_t)v[0];
        t[base + 1] = (bf16_t)v[1];
        t[base + 2] = (bf16_t)v[2];
        t[base + 3] = (bf16_t)v[3];
    }
    __syncthreads();
#pragma unroll
    for (int i = 0; i < 2; ++i) {
        int c = tid + 256 * i;
        int n = c >> 3;
        int ck = c & 7;
        union { bf16_t h[8]; uint4 u; } cv;
#pragma unroll
        for (int j = 0; j < 8; ++j) cv.h[j] = t[(ck * 8 + j) * 66 + n];
        *reinterpret_cast<uint4*>(o + (size_t)(n0 + n) * DM + k0 + ck * 8) = cv.u;
    }
}

// ====== fused QKV projection: 128x64 tiles, f32-A direct staging (cast fused) ====
struct QKVArgs {
    const float* A[3]; const bf16_t* BT[3]; const float* bias[3];
    bf16_t* out[3]; float alpha0;
};

__global__ __launch_bounds__(256) void gemm_qkv(QKVArgs a) {
    constexpr int K = 1024;
    int bid = blockIdx.x;
    int wi = bid >> 10;
    int sub = bid & 1023;
    int bm = (sub & 7) * 8 + ((sub >> 3) & 7);   // [0,64)  XCD-grouped
    int bn = sub >> 6;                           // [0,16)
    int tid = threadIdx.x;
    int w = tid >> 6, l = tid & 63;
    int g = l >> 4, lc = l & 15;

    const float* Af = a.A[wi];
    const bf16_t* BT = a.BT[wi];

    __shared__ float  a_buf[2][128 * 32];        // 16 KB x2 (f32 tile)
    __shared__ bf16_t b_buf[2][64 * 32];         // 4 KB x2  -> 40 KB total

    f32x4 zero = {0.f, 0.f, 0.f, 0.f};
    f32x4 acc[4][2];
#pragma unroll
    for (int m = 0; m < 4; ++m)
#pragma unroll
        for (int n = 0; n < 2; ++n) acc[m][n] = zero;

    int m0 = bm * 128, n0 = bn * 64;
    int wr = (w >> 1) * 64, wc = (w & 1) * 32;

    int sc8 = (l & 7) ^ (l >> 3);                // A: pre-swizzled src chunk [0,8)
    int scw = (l & 3) ^ ((l >> 3) & 3);          // B: pre-swizzled src chunk [0,4)
    int sw8 = lc & 7;                            // A read-side swizzle key
    int fsw = (lc >> 1) & 3;                     // B read-side swizzle key

    auto stage = [&](int buf, int kt) {          // 5 gl_lds per thread
        int k0 = kt * 32;
#pragma unroll
        for (int i = 0; i < 4; ++i) {
            int r8 = (w * 4 + i) * 8;            // 8 f32 rows per issue
            int row = r8 + (l >> 3);
            gl_lds16(Af + (size_t)(m0 + row) * K + k0 + sc8 * 4, &a_buf[buf][r8 * 32]);
        }
        int r16 = w * 16;
        int row = r16 + (l >> 2);
        gl_lds16(BT + (size_t)(n0 + row) * K + k0 + scw * 8, &b_buf[buf][r16 * 32]);
    };

    stage(0, 0);
    int cur = 0;
    for (int kt = 0; kt < K / 32; ++kt) {
        __syncthreads();
        if (kt + 1 < K / 32) stage(cur ^ 1, kt + 1);
        bf16x8 af[4], bfr[2];
#pragma unroll
        for (int m = 0; m < 4; ++m) {
            const float* base = &a_buf[cur][(wr + m * 16 + lc) * 32];
            f32x4 lo = *reinterpret_cast<const f32x4*>(base + (((2 * g) ^ sw8) << 2));
            f32x4 hi = *reinterpret_cast<const f32x4*>(base + (((2 * g + 1) ^ sw8) << 2));
            union { bf16_t h[8]; bf16x8 v; } cv;
#pragma unroll
            for (int j = 0; j < 4; ++j) { cv.h[j] = (bf16_t)lo[j]; cv.h[4 + j] = (bf16_t)hi[j]; }
            af[m] = cv.v;
        }
#pragma unroll
        for (int n = 0; n < 2; ++n)
            bfr[n] = *reinterpret_cast<bf16x8*>(
                &b_buf[cur][(wc + n * 16 + lc) * 32 + (g ^ fsw) * 8]);
#pragma unroll
        for (int m = 0; m < 4; ++m)
#pragma unroll
            for (int n = 0; n < 2; ++n)
                acc[m][n] = MFMA16(af[m], bfr[n], acc[m][n]);
        cur ^= 1;
    }

    float alpha = (wi == 0) ? a.alpha0 : 1.0f;
    const float* bias = a.bias[wi];
    bf16_t* Cp = a.out[wi];
    if (wi == 2) {
        // V: transposed [B][H][dh][S], packed 8B stores
#pragma unroll
        for (int n = 0; n < 2; ++n) {
            int ng = n0 + wc + n * 16 + lc;
            float bv = bias[ng];
            int h = ng >> 6, d = ng & 63;
#pragma unroll
            for (int m = 0; m < 4; ++m) {
                int s0g = m0 + wr + m * 16 + g * 4;
                int b = s0g >> 11, s0 = s0g & 2047;
                union { bf16_t hh[4]; uint2 u; } pk;
#pragma unroll
                for (int r = 0; r < 4; ++r)
                    pk.hh[r] = (bf16_t)(acc[m][n][r] + bv);
                *reinterpret_cast<uint2*>(
                    &Cp[(((size_t)(b * NH + h)) * DH + d) * S_LEN + s0]) = pk.u;
            }
        }
    } else {
        // Q/K: [B][H][S][dh]
#pragma unroll
        for (int n = 0; n < 2; ++n) {
            int ng = n0 + wc + n * 16 + lc;
            float bv = bias[ng];
            int h = ng >> 6, d = ng & 63;
#pragma unroll
            for (int m = 0; m < 4; ++m) {
#pragma unroll
                for (int r = 0; r < 4; ++r) {
                    int mg = m0 + wr + m * 16 + g * 4 + r;
                    int b = mg >> 11, s = mg & 2047;
                    Cp[(((size_t)(b * NH + h)) * S_LEN + s) * DH + d] =
                        (bf16_t)((acc[m][n][r] + bv) * alpha);
                }
            }
        }
    }
}

// ======== final projection: C[M][1024] f32, 128x64 tiles + T2 chunk-swizzle ======
__global__ __launch_bounds__(256) void gemm_o(const bf16_t* __restrict__ Ab,
                                              const bf16_t* __restrict__ BT,
                                              const float* __restrict__ bias,
                                              float* __restrict__ Cp) {
    constexpr int K = 1024, N = 1024;
    int bid = blockIdx.x;
    int bm = (bid & 7) * 8 + ((bid >> 3) & 7);
    int bn = bid >> 6;
    int tid = threadIdx.x;
    int w = tid >> 6, l = tid & 63;
    int g = l >> 4, lc = l & 15;

    __shared__ bf16_t a_buf[2][128 * 32];
    __shared__ bf16_t b_buf[2][64 * 32];

    f32x4 zero = {0.f, 0.f, 0.f, 0.f};
    f32x4 acc[4][2];
#pragma unroll
    for (int m = 0; m < 4; ++m)
#pragma unroll
        for (int n = 0; n < 2; ++n) acc[m][n] = zero;

    int m0 = bm * 128, n0 = bn * 64;
    int wr = (w >> 1) * 64, wc = (w & 1) * 32;

    int scw = (l & 3) ^ ((l >> 3) & 3);
    int fsw = (lc >> 1) & 3;

    auto stage = [&](int buf, int kt) {
        int k0 = kt * 32;
#pragma unroll
        for (int i = 0; i < 2; ++i) {
            int r16 = (w * 2 + i) * 16;
            int row = r16 + (l >> 2);
            gl_lds16(Ab + (size_t)(m0 + row) * K + k0 + scw * 8, &a_buf[buf][r16 * 32]);
        }
        int r16 = w * 16;
        int row = r16 + (l >> 2);
        gl_lds16(BT + (size_t)(n0 + row) * K + k0 + scw * 8, &b_buf[buf][r16 * 32]);
    };

    stage(0, 0);
    int cur = 0;
    for (int kt = 0; kt < K / 32; ++kt) {
        __syncthreads();
        if (kt + 1 < K / 32) stage(cur ^ 1, kt + 1);
        bf16x8 af[4], bfr[2];
#pragma unroll
        for (int m = 0; m < 4; ++m)
            af[m] = *reinterpret_cast<bf16x8*>(
                &a_buf[cur][(wr + m * 16 + lc) * 32 + (g ^ fsw) * 8]);
#pragma unroll
        for (int n = 0; n < 2; ++n)
            bfr[n] = *reinterpret_cast<bf16x8*>(
                &b_buf[cur][(wc + n * 16 + lc) * 32 + (g ^ fsw) * 8]);
#pragma unroll
        for (int m = 0; m < 4; ++m)
#pragma unroll
            for (int n = 0; n < 2; ++n)
                acc[m][n] = MFMA16(af[m], bfr[n], acc[m][n]);
        cur ^= 1;
    }

#pragma unroll
    for (int n = 0; n < 2; ++n) {
        int ng = n0 + wc + n * 16 + lc;
        float bv = bias[ng];
#pragma unroll
        for (int m = 0; m < 4; ++m) {
#pragma unroll
            for (int r = 0; r < 4; ++r) {
                int mg = m0 + wr + m * 16 + g * 4 + r;
                Cp[(size_t)mg * N + ng] = acc[m][n][r] + bv;
            }
        }
    }
}

// ======= causal flash attention (2048 blocks, descending, hoisted pointers) ======
__global__ __launch_bounds__(256) void attn_kernel(const bf16_t* __restrict__ Qh,
                                                   const bf16_t* __restrict__ Kh,
                                                   const bf16_t* __restrict__ Vt,
                                                   bf16_t* __restrict__ AO) {
    int bid = blockIdx.x;
    int qt = 31 - (bid >> 6);
    int bh = bid & 63;
    int h = bh & 15;
    int b = bh >> 4;
    int tid = threadIdx.x;
    int w = tid >> 6, l = tid & 63;
    int g = l >> 4, lc = l & 15;
    int q0 = qt * 64 + w * 16;
    int q = q0 + lc;

    __shared__ bf16_t k_lds[2][64 * 64];
    __shared__ bf16_t v_lds[2][64 * 64];
    __shared__ bf16_t p_lds[4][16 * 64];

    size_t head_off = ((size_t)(b * NH + h)) * S_LEN * DH;

    bf16x8 qf[2];
    {
        const bf16_t* qp = Qh + head_off + (size_t)(q0 + lc) * DH + g * 8;
        qf[0] = *reinterpret_cast<const bf16x8*>(qp);
        qf[1] = *reinterpret_cast<const bf16x8*>(qp + 32);
    }

    const bf16_t* kg0; const bf16_t* kg1; const bf16_t* vg0; const bf16_t* vg1;
    int r8a = w * 16, r8b = w * 16 + 8;
    {
        const bf16_t* Kp = Kh + head_off;
        const bf16_t* Vp = Vt + head_off;
        int rowa = r8a + (l >> 3), rowb = r8b + (l >> 3);
        int sca = (l & 7) ^ (rowa & 7), scb = (l & 7) ^ (rowb & 7);
        kg0 = Kp + (size_t)rowa * DH + sca * 8;
        kg1 = Kp + (size_t)rowb * DH + scb * 8;
        vg0 = Vp + (size_t)rowa * S_LEN + sca * 8;
        vg1 = Vp + (size_t)rowb * S_LEN + scb * 8;
    }

    f32x4 zero = {0.f, 0.f, 0.f, 0.f};
    f32x4 o_acc[4];
#pragma unroll
    for (int nt = 0; nt < 4; ++nt) o_acc[nt] = zero;
    float l_part = 0.f;

    int sw = lc & 7;

    auto stageKV = [&](int buf) {
        gl_lds16(kg0, &k_lds[buf][r8a * 64]);
        gl_lds16(vg0, &v_lds[buf][r8a * 64]);
        gl_lds16(kg1, &k_lds[buf][r8b * 64]);
        gl_lds16(vg1, &v_lds[buf][r8b * 64]);
    };

    stageKV(0);
    int cur = 0;
    for (int t = 0; t <= qt; ++t) {
        int kv0 = t * 64;
        __syncthreads();
        if (t < qt) {
            kg0 += 64 * DH; kg1 += 64 * DH; vg0 += 64; vg1 += 64;
            stageKV(cur ^ 1);
        }

        f32x4 sc[4];
#pragma unroll
        for (int nt = 0; nt < 4; ++nt) {
            int row = nt * 16 + lc;
            bf16x8 kf0 = *reinterpret_cast<bf16x8*>(&k_lds[cur][row * 64 + ((g) ^ sw) * 8]);
            bf16x8 kf1 = *reinterpret_cast<bf16x8*>(&k_lds[cur][row * 64 + ((4 + g) ^ sw) * 8]);
            f32x4 s = zero;
            s = MFMA16(kf0, qf[0], s);
            s = MFMA16(kf1, qf[1], s);
            sc[nt] = s;
        }
        if (t == qt) {
#pragma unroll
            for (int nt = 0; nt < 4; ++nt)
#pragma unroll
                for (int r = 0; r < 4; ++r) {
                    int kv = kv0 + nt * 16 + g * 4 + r;
                    if (kv > q) sc[nt][r] = -1e30f;
                }
        }
#pragma unroll
        for (int nt = 0; nt < 4; ++nt)
#pragma unroll
            for (int r = 0; r < 4; ++r) sc[nt][r] = exp2f(sc[nt][r]);
#pragma unroll
        for (int nt = 0; nt < 4; ++nt)
            l_part += sc[nt][0] + sc[nt][1] + sc[nt][2] + sc[nt][3];
#pragma unroll
        for (int nt = 0; nt < 4; ++nt) {
            union { bf16_t hh[4]; uint2 u; } pk;
#pragma unroll
            for (int r = 0; r < 4; ++r) pk.hh[r] = (bf16_t)sc[nt][r];
            int cu = nt * 2 + (g >> 1);
            *reinterpret_cast<uint2*>(
                &p_lds[w][lc * 64 + ((cu ^ sw) * 8) + (g & 1) * 4]) = pk.u;
        }
        bf16x8 pf0 = *reinterpret_cast<bf16x8*>(&p_lds[w][lc * 64 + ((g) ^ sw) * 8]);
        bf16x8 pf1 = *reinterpret_cast<bf16x8*>(&p_lds[w][lc * 64 + ((4 + g) ^ sw) * 8]);
#pragma unroll
        for (int nt = 0; nt < 4; ++nt) {
            int row = nt * 16 + lc;
            bf16x8 vf0 = *reinterpret_cast<bf16x8*>(&v_lds[cur][row * 64 + ((g) ^ sw) * 8]);
            bf16x8 vf1 = *reinterpret_cast<bf16x8*>(&v_lds[cur][row * 64 + ((4 + g) ^ sw) * 8]);
            o_acc[nt] = MFMA16(pf0, vf0, o_acc[nt]);
            o_acc[nt] = MFMA16(pf1, vf1, o_acc[nt]);
        }
        cur ^= 1;
    }

    float l_s = l_part;
    l_s += __shfl_xor(l_s, 16, 64);
    l_s += __shfl_xor(l_s, 32, 64);

#pragma unroll
    for (int r = 0; r < 4; ++r) {
        float lr = __shfl(l_s, g * 4 + r, 64);
        float inv = 1.0f / lr;
        int qq = q0 + g * 4 + r;
        size_t base = ((size_t)b * S_LEN + qq) * DM + h * DH;
#pragma unroll
        for (int nt = 0; nt < 4; ++nt)
            AO[base + nt * 16 + lc] = (bf16_t)(o_acc[nt][r] * inv);
    }
}

// ================= launch =================
extern "C" void kernel_launch(void* const* d_in, const int* in_sizes, int n_in,
                              void* d_out, int out_size, void* d_ws, size_t ws_size,
                              hipStream_t stream) {
    (void)in_sizes; (void)n_in; (void)out_size; (void)ws_size;
    const float* query = (const float*)d_in[0];
    const float* key   = (const float*)d_in[1];
    const float* value = (const float*)d_in[2];
    const float* wq = (const float*)d_in[3];
    const float* bq = (const float*)d_in[4];
    const float* wk = (const float*)d_in[5];
    const float* bk = (const float*)d_in[6];
    const float* wv = (const float*)d_in[7];
    const float* bv = (const float*)d_in[8];
    const float* wo = (const float*)d_in[9];
    const float* bo = (const float*)d_in[10];
    float* out = (float*)d_out;

    char* ws = (char*)d_ws;
    const size_t Mi = (size_t)1 << 20;
    bf16_t* wqT = (bf16_t*)(ws + 0 * Mi);
    bf16_t* wkT = (bf16_t*)(ws + 2 * Mi);
    bf16_t* wvT = (bf16_t*)(ws + 4 * Mi);
    bf16_t* woT = (bf16_t*)(ws + 6 * Mi);
    bf16_t* Qh  = (bf16_t*)(ws + 8 * Mi);   // [B][H][S][64]
    bf16_t* Kh  = (bf16_t*)(ws + 24 * Mi);  // [B][H][S][64]
    bf16_t* Vt  = (bf16_t*)(ws + 40 * Mi);  // [B][H][64][S]
    bf16_t* AO  = (bf16_t*)(ws + 56 * Mi);  // [B][S][1024]

    const float QALPHA = 0.04508422f;        // log2(e)/32

    PreArgs p;
    p.w[0] = wq; p.w[1] = wk; p.w[2] = wv; p.w[3] = wo;
    p.o[0] = wqT; p.o[1] = wkT; p.o[2] = wvT; p.o[3] = woT;
    pre_kernel<<<dim3(1024), dim3(256), 0, stream>>>(p);

    QKVArgs qa;
    qa.A[0] = query; qa.A[1] = key; qa.A[2] = value;
    qa.BT[0] = wqT; qa.BT[1] = wkT; qa.BT[2] = wvT;
    qa.bias[0] = bq; qa.bias[1] = bk; qa.bias[2] = bv;
    qa.out[0] = Qh; qa.out[1] = Kh; qa.out[2] = Vt;
    qa.alpha0 = QALPHA;
    gemm_qkv<<<dim3(3 * 1024), dim3(256), 0, stream>>>(qa);

    attn_kernel<<<dim3(2048), dim3(256), 0, stream>>>(Qh, Kh, Vt, AO);

    gemm_o<<<dim3(1024), dim3(256), 0, stream>>>(AO, woT, bo, out);
}